// Round 4
// baseline (750.832 us; speedup 1.0000x reference)
//
#include <hip/hip_runtime.h>
#include <math.h>

// N=50000, E=800000, IN=128, H=4, C=64, HC=256
#define HEADS 4
#define CH 64
#define HC 256

typedef short bf16x8 __attribute__((ext_vector_type(8)));
typedef float f32x4 __attribute__((ext_vector_type(4)));

__device__ __forceinline__ float leaky02(float x) { return x > 0.f ? x : 0.2f * x; }
__device__ __forceinline__ float bf2f(unsigned short u) {
  unsigned int v = ((unsigned int)u) << 16;
  return __builtin_bit_cast(float, v);
}
__device__ __forceinline__ unsigned short f2bf(float f) {
  unsigned int u = __builtin_bit_cast(unsigned int, f);
  unsigned int r = u + 0x7fffu + ((u >> 16) & 1u);
  return (unsigned short)(r >> 16);
}
__device__ __forceinline__ float decode_max(unsigned int key) {
  unsigned int mb = (key & 0x80000000u) ? (key & 0x7fffffffu) : ~key;
  return __builtin_bit_cast(float, mb);
}

// ---------------------------------------------------------------------------
// Convert input x fp32 [N*128] -> bf16
// ---------------------------------------------------------------------------
__global__ __launch_bounds__(256) void convert_x(const float* __restrict__ x,
                                                 unsigned short* __restrict__ xb,
                                                 int total4) {
  int i = blockIdx.x * 256 + threadIdx.x;
  if (i >= total4) return;
  float4 v = reinterpret_cast<const float4*>(x)[i];
  ushort4 o;
  o.x = f2bf(v.x); o.y = f2bf(v.y); o.z = f2bf(v.z); o.w = f2bf(v.w);
  reinterpret_cast<ushort4*>(xb)[i] = o;
}

// ---------------------------------------------------------------------------
// LDS-tiled transpose: Bt[512][K] bf16 = [W | SW]^T  (W/SW are [K][256] fp32)
// ---------------------------------------------------------------------------
__global__ __launch_bounds__(256) void transpose_w(const float* __restrict__ W,
                                                   const float* __restrict__ SW,
                                                   unsigned short* __restrict__ Bt, int K) {
  __shared__ unsigned short tile[64][72];
  int k0 = blockIdx.x * 64;
  int c0 = blockIdx.y * 64;
  const float* __restrict__ src = (c0 < 256) ? W : SW;
  int cc = (c0 < 256) ? c0 : c0 - 256;

  int t = threadIdx.x;
  int r = t >> 2, q4 = (t & 3) * 16;
#pragma unroll
  for (int q = 0; q < 4; q++) {
    float4 v = *reinterpret_cast<const float4*>(src + (size_t)(k0 + r) * 256 + cc + q4 + q * 4);
    tile[q4 + q * 4 + 0][r] = f2bf(v.x);
    tile[q4 + q * 4 + 1][r] = f2bf(v.y);
    tile[q4 + q * 4 + 2][r] = f2bf(v.z);
    tile[q4 + q * 4 + 3][r] = f2bf(v.w);
  }
  __syncthreads();
  int c = t >> 2, kq = (t & 3) * 16;
#pragma unroll
  for (int q = 0; q < 2; q++) {
    bf16x8 v = *reinterpret_cast<const bf16x8*>(&tile[c][kq + q * 8]);
    *reinterpret_cast<bf16x8*>(Bt + (size_t)(c0 + c) * K + k0 + kq + q * 8) = v;
  }
}

// ---------------------------------------------------------------------------
// bf16 MFMA GEMM + fused s/d epilogue.
// out[M][512] = x[M][K] @ [W|SW][K][512]
//   colBase=0  : cols 0..255 -> h (bf16) + s,d per (row,head) (plain stores)
//   colBase=256: cols 256..511 -> skip (bf16, +Sb)
// 128 rows x 256 cols per block, BK=32, 4 waves, wave tile 64x128.
// ---------------------------------------------------------------------------
__global__ __launch_bounds__(256) void gemm_mfma(
    const unsigned short* __restrict__ xb, const unsigned short* __restrict__ Bt,
    const float* __restrict__ Sb, const float* __restrict__ a_src,
    const float* __restrict__ a_dst, unsigned short* __restrict__ h,
    unsigned short* __restrict__ skipb, float* __restrict__ sbuf,
    float* __restrict__ dbuf, int M, int K) {
  __shared__ unsigned short As[128 * 40];
  __shared__ unsigned short Bs[256 * 40];

  const int t = threadIdx.x;
  const int rowBase = blockIdx.y * 128;
  const int colBase = blockIdx.x * 256;
  const int w = t >> 6, lane = t & 63;
  const int wr = (w >> 1) * 64;    // 0 or 64 (rows)
  const int wc = (w & 1) * 128;    // 0 or 128 (cols within 256)
  const int lrow = lane & 15, lq = lane >> 4;

  f32x4 acc[4][8];
#pragma unroll
  for (int i = 0; i < 4; i++)
#pragma unroll
    for (int j = 0; j < 8; j++) acc[i][j] = (f32x4){0.f, 0.f, 0.f, 0.f};

  for (int k0 = 0; k0 < K; k0 += 32) {
    // Stage A: 128 rows x 32 k
#pragma unroll
    for (int p = 0; p < 2; p++) {
      int flat = t + p * 256;
      int r = flat >> 2, seg = flat & 3;
      int gr = rowBase + r;
      if (gr >= M) gr = M - 1;
      bf16x8 av = *reinterpret_cast<const bf16x8*>(xb + (size_t)gr * K + k0 + seg * 8);
      *reinterpret_cast<bf16x8*>(&As[r * 40 + seg * 8]) = av;
    }
    // Stage B: 256 cols x 32 k
#pragma unroll
    for (int p = 0; p < 4; p++) {
      int flat = t + p * 256;
      int r = flat >> 2, seg = flat & 3;
      int gc = colBase + r;
      bf16x8 bv = *reinterpret_cast<const bf16x8*>(Bt + (size_t)gc * K + k0 + seg * 8);
      *reinterpret_cast<bf16x8*>(&Bs[r * 40 + seg * 8]) = bv;
    }
    __syncthreads();

    bf16x8 af[4], bfr[8];
#pragma unroll
    for (int i = 0; i < 4; i++)
      af[i] = *reinterpret_cast<const bf16x8*>(&As[(wr + i * 16 + lrow) * 40 + lq * 8]);
#pragma unroll
    for (int j = 0; j < 8; j++)
      bfr[j] = *reinterpret_cast<const bf16x8*>(&Bs[(wc + j * 16 + lrow) * 40 + lq * 8]);
#pragma unroll
    for (int i = 0; i < 4; i++)
#pragma unroll
      for (int j = 0; j < 8; j++)
        acc[i][j] = __builtin_amdgcn_mfma_f32_16x16x32_bf16(af[i], bfr[j], acc[i][j], 0, 0, 0);
    __syncthreads();
  }

  if (colBase == 0) {
    // h store + fused s/d partials
    float as_v[8], ad_v[8];
#pragma unroll
    for (int j = 0; j < 8; j++) {
      int c = wc + j * 16 + lrow;
      as_v[j] = a_src[c];
      ad_v[j] = a_dst[c];
    }
    float sp_s[2][4][4];
    float sp_d[2][4][4];
#pragma unroll
    for (int hh = 0; hh < 2; hh++)
#pragma unroll
      for (int i = 0; i < 4; i++)
#pragma unroll
        for (int r = 0; r < 4; r++) { sp_s[hh][i][r] = 0.f; sp_d[hh][i][r] = 0.f; }

#pragma unroll
    for (int i = 0; i < 4; i++) {
#pragma unroll
      for (int j = 0; j < 8; j++) {
        int gcol = wc + j * 16 + lrow;
#pragma unroll
        for (int r = 0; r < 4; r++) {
          int grow = rowBase + wr + i * 16 + lq * 4 + r;
          float v = acc[i][j][r];
          if (grow < M) h[(size_t)grow * 256 + gcol] = f2bf(v);
          sp_s[j >> 2][i][r] += v * as_v[j];
          sp_d[j >> 2][i][r] += v * ad_v[j];
        }
      }
    }
    // reduce over the 16 lrow lanes
#pragma unroll
    for (int mask = 1; mask <= 8; mask <<= 1) {
#pragma unroll
      for (int hh = 0; hh < 2; hh++)
#pragma unroll
        for (int i = 0; i < 4; i++)
#pragma unroll
          for (int r = 0; r < 4; r++) {
            sp_s[hh][i][r] += __shfl_xor(sp_s[hh][i][r], mask, 64);
            sp_d[hh][i][r] += __shfl_xor(sp_d[hh][i][r], mask, 64);
          }
    }
    if (lrow == 0) {
      int headBase = wc >> 6;  // 0 or 2
#pragma unroll
      for (int hh = 0; hh < 2; hh++)
#pragma unroll
        for (int i = 0; i < 4; i++)
#pragma unroll
          for (int r = 0; r < 4; r++) {
            int grow = rowBase + wr + i * 16 + lq * 4 + r;
            if (grow < M) {
              sbuf[grow * 4 + headBase + hh] = sp_s[hh][i][r];
              dbuf[grow * 4 + headBase + hh] = sp_d[hh][i][r];
            }
          }
    }
  } else {
    // skip store (bf16, +Sb)
#pragma unroll
    for (int i = 0; i < 4; i++) {
#pragma unroll
      for (int j = 0; j < 8; j++) {
        int c = wc + j * 16 + lrow;
        float sbv = Sb[c];
#pragma unroll
        for (int r = 0; r < 4; r++) {
          int grow = rowBase + wr + i * 16 + lq * 4 + r;
          if (grow < M) skipb[(size_t)grow * 256 + c] = f2bf(acc[i][j][r] + sbv);
        }
      }
    }
  }
}

// ---------------------------------------------------------------------------
// Global per-head max of s
// ---------------------------------------------------------------------------
__global__ __launch_bounds__(256) void smax_kernel(const float* __restrict__ s,
                                                   unsigned int* __restrict__ smax_enc,
                                                   int total) {
  __shared__ float sm[256];
  int t = threadIdx.x;
  int i = blockIdx.x * 256 + t;
  sm[t] = (i < total) ? s[i] : -1e30f;
  __syncthreads();
  for (int off = 128; off >= 4; off >>= 1) {
    if (t < off) sm[t] = fmaxf(sm[t], sm[t + off]);
    __syncthreads();
  }
  if (t < 4) {
    unsigned int b = __builtin_bit_cast(unsigned int, sm[t]);
    unsigned int key = (b & 0x80000000u) ? ~b : (b | 0x80000000u);
    atomicMax(&smax_enc[t], key);
  }
}

// ---------------------------------------------------------------------------
// CSR build (padded to multiple-of-8 segments)
// ---------------------------------------------------------------------------
__global__ void hist_kernel(const int* __restrict__ ei, int* __restrict__ counts, int E) {
  int e = blockIdx.x * 256 + threadIdx.x;
  if (e < E) atomicAdd(&counts[ei[E + e]], 1);
}

__global__ __launch_bounds__(1024) void scan_kernel(
    const int* __restrict__ counts, int* __restrict__ offsets,
    int* __restrict__ cursor, int n) {
  __shared__ int wsums[16];
  __shared__ int srun;
  int tid = threadIdx.x;
  int lane = tid & 63, wv = tid >> 6;
  if (tid == 0) srun = 0;
  __syncthreads();
  for (int base = 0; base < n; base += 1024) {
    int i = base + tid;
    int c = (i < n) ? counts[i] : 0;
    int v = (c + 7) & ~7;  // pad each segment to multiple of 8
    int incl = v;
#pragma unroll
    for (int off = 1; off < 64; off <<= 1) {
      int tv = __shfl_up(incl, off, 64);
      if (lane >= off) incl += tv;
    }
    if (lane == 63) wsums[wv] = incl;
    __syncthreads();
    if (wv == 0) {
      int wval = (lane < 16) ? wsums[lane] : 0;
      int winc = wval;
#pragma unroll
      for (int off = 1; off < 16; off <<= 1) {
        int tv = __shfl_up(winc, off, 64);
        if (lane >= off) winc += tv;
      }
      if (lane < 16) wsums[lane] = winc - wval;
    }
    __syncthreads();
    int excl = srun + wsums[wv] + incl - v;
    if (i < n) { offsets[i] = excl; cursor[i] = excl; }
    __syncthreads();
    if (tid == 1023) srun = excl + v;
    __syncthreads();
  }
  if (tid == 0) offsets[n] = srun;
}

__global__ void scatter_kernel(const int* __restrict__ ei, int* __restrict__ cursor,
                               int* __restrict__ csr, int* __restrict__ csr_dst, int E) {
  int e = blockIdx.x * 256 + threadIdx.x;
  if (e < E) {
    int dn = ei[E + e];
    int pos = atomicAdd(&cursor[dn], 1);
    csr[pos] = ei[e];
    csr_dst[pos] = dn;
  }
}

__global__ void pad_kernel(const int* __restrict__ counts, const int* __restrict__ offsets,
                           int* __restrict__ csr, int* __restrict__ csr_dst, int Nn) {
  int n = blockIdx.x * 256 + threadIdx.x;
  if (n >= Nn) return;
  int e0 = offsets[n] + counts[n];
  int e1 = offsets[n + 1];
  for (int i = e0; i < e1; i++) { csr[i] = 0; csr_dst[i] = -1; }
}

// ---------------------------------------------------------------------------
// Per-slot softmax numerators, 4 head planes
// ---------------------------------------------------------------------------
__global__ __launch_bounds__(256) void edge_e_kernel(
    const int* __restrict__ csr, const int* __restrict__ csr_dst,
    const float* __restrict__ s, const float* __restrict__ d,
    const unsigned int* __restrict__ smax_enc, float* __restrict__ eexp,
    int eps, const int* __restrict__ etot_ptr) {
  int i = blockIdx.x * 256 + threadIdx.x;
  if (i >= etot_ptr[0]) return;
  int dn = csr_dst[i];
  if (dn < 0) {
    eexp[i] = 0.f; eexp[eps + i] = 0.f; eexp[2 * eps + i] = 0.f; eexp[3 * eps + i] = 0.f;
    return;
  }
  int sn = csr[i];
  float4 s4 = *reinterpret_cast<const float4*>(s + sn * 4);
  float4 d4 = *reinterpret_cast<const float4*>(d + dn * 4);
  eexp[0 * eps + i] = __expf(leaky02(s4.x + d4.x) - leaky02(decode_max(smax_enc[0]) + d4.x));
  eexp[1 * eps + i] = __expf(leaky02(s4.y + d4.y) - leaky02(decode_max(smax_enc[1]) + d4.y));
  eexp[2 * eps + i] = __expf(leaky02(s4.z + d4.z) - leaky02(decode_max(smax_enc[2]) + d4.z));
  eexp[3 * eps + i] = __expf(leaky02(s4.w + d4.w) - leaky02(decode_max(smax_enc[3]) + d4.w));
}

// ---------------------------------------------------------------------------
// Aggregation v4: one wave per node; 32 lanes per edge-row (8 cols/lane, b128
// gathers); the two wave halves take interleaved 4-edge groups (segments are
// padded to multiples of 8 so halves are balanced); combine via shfl_xor(32).
// ---------------------------------------------------------------------------
__global__ __launch_bounds__(256) void agg_kernel(
    const unsigned short* __restrict__ hb, const float* __restrict__ s,
    const float* __restrict__ d, const unsigned int* __restrict__ smax_enc,
    const int* __restrict__ offsets, const int* __restrict__ csr,
    const float* __restrict__ eexp, int eps,
    const float* __restrict__ b, const unsigned short* __restrict__ skipb,
    float* __restrict__ xout_f, unsigned short* __restrict__ xout_b,
    int Nn, int write_f) {
  int n = blockIdx.x * 4 + (threadIdx.x >> 6);
  if (n >= Nn) return;
  int lane = threadIdx.x & 63;
  int sub = lane >> 5;      // which half
  int li = lane & 31;
  int head = li >> 3;
  int col = li * 8;

  int beg = offsets[n], end = offsets[n + 1];
  const float* __restrict__ eh = eexp + head * eps;

  float a[8] = {0.f, 0.f, 0.f, 0.f, 0.f, 0.f, 0.f, 0.f};
  float dsum = 0.f;

  for (int i = beg + sub * 4; i < end; i += 8) {
    int4 sn = *reinterpret_cast<const int4*>(csr + i);
    float4 ev = *reinterpret_cast<const float4*>(eh + i);
    bf16x8 u0 = *reinterpret_cast<const bf16x8*>(hb + (size_t)sn.x * HC + col);
    bf16x8 u1 = *reinterpret_cast<const bf16x8*>(hb + (size_t)sn.y * HC + col);
    bf16x8 u2 = *reinterpret_cast<const bf16x8*>(hb + (size_t)sn.z * HC + col);
    bf16x8 u3 = *reinterpret_cast<const bf16x8*>(hb + (size_t)sn.w * HC + col);
#pragma unroll
    for (int k = 0; k < 8; k++) {
      a[k] += ev.x * bf2f((unsigned short)u0[k]) + ev.y * bf2f((unsigned short)u1[k]) +
              ev.z * bf2f((unsigned short)u2[k]) + ev.w * bf2f((unsigned short)u3[k]);
    }
    dsum += ev.x + ev.y + ev.z + ev.w;
  }

  // combine halves
#pragma unroll
  for (int k = 0; k < 8; k++) a[k] += __shfl_xor(a[k], 32, 64);
  dsum += __shfl_xor(dsum, 32, 64);

  // self loop
  float sv = s[n * 4 + head], dv = d[n * 4 + head];
  float m = leaky02(decode_max(smax_enc[head]) + dv);
  float es = __expf(leaky02(sv + dv) - m);
  bf16x8 hs = *reinterpret_cast<const bf16x8*>(hb + (size_t)n * HC + col);
#pragma unroll
  for (int k = 0; k < 8; k++) a[k] += es * bf2f((unsigned short)hs[k]);
  dsum += es;

  if (sub == 0) {
    float inv = 1.f / (dsum + 1e-16f);
    bf16x8 sk = *reinterpret_cast<const bf16x8*>(skipb + (size_t)n * HC + col);
    float4 b0 = *reinterpret_cast<const float4*>(b + col);
    float4 b1 = *reinterpret_cast<const float4*>(b + col + 4);
    float bv[8] = {b0.x, b0.y, b0.z, b0.w, b1.x, b1.y, b1.z, b1.w};
    float res[8];
#pragma unroll
    for (int k = 0; k < 8; k++) {
      float v = a[k] * inv + bv[k] + bf2f((unsigned short)sk[k]);
      res[k] = v > 0.f ? v : expm1f(v);
    }
    if (write_f) {
      float4 r0 = make_float4(res[0], res[1], res[2], res[3]);
      float4 r1 = make_float4(res[4], res[5], res[6], res[7]);
      *reinterpret_cast<float4*>(xout_f + (size_t)n * HC + col) = r0;
      *reinterpret_cast<float4*>(xout_f + (size_t)n * HC + col + 4) = r1;
    } else {
      bf16x8 o;
#pragma unroll
      for (int k = 0; k < 8; k++) o[k] = (short)f2bf(res[k]);
      *reinterpret_cast<bf16x8*>(xout_b + (size_t)n * HC + col) = o;
    }
  }
}

// ---------------------------------------------------------------------------
extern "C" void kernel_launch(void* const* d_in, const int* in_sizes, int n_in,
                              void* d_out, int out_size, void* d_ws, size_t ws_size,
                              hipStream_t stream) {
  const float* x = (const float*)d_in[0];
  const int* ei = (const int*)d_in[1];
  const int Nn = in_sizes[0] / 128;  // 50000
  const int E = in_sizes[1] / 2;     // 800000
  const int EPS = E + 7 * Nn;        // max padded CSR size (pad-8)

  const float* W[3]; const float* asrc[3]; const float* adst[3];
  const float* bb[3]; const float* SW[3]; const float* Sb[3];
  for (int l = 0; l < 3; l++) {
    W[l]    = (const float*)d_in[2 + 6 * l + 0];
    asrc[l] = (const float*)d_in[2 + 6 * l + 1];
    adst[l] = (const float*)d_in[2 + 6 * l + 2];
    bb[l]   = (const float*)d_in[2 + 6 * l + 3];
    SW[l]   = (const float*)d_in[2 + 6 * l + 4];
    Sb[l]   = (const float*)d_in[2 + 6 * l + 5];
  }

  // Workspace layout (16B aligned chunks)
  char* p = (char*)d_ws;
  unsigned short* hb    = (unsigned short*)p; p += (size_t)Nn * HC * 2;
  unsigned short* xb    = (unsigned short*)p; p += (size_t)Nn * HC * 2;
  unsigned short* x1b   = (unsigned short*)p; p += (size_t)Nn * 128 * 2;
  unsigned short* Bt    = (unsigned short*)p; p += (size_t)512 * 256 * 2;
  unsigned short* skipb = (unsigned short*)p; p += (size_t)Nn * HC * 2;
  float* sbuf  = (float*)p; p += (size_t)Nn * HEADS * 4;
  float* dbuf  = (float*)p; p += (size_t)Nn * HEADS * 4;
  float* eexp  = (float*)p; p += (size_t)4 * EPS * 4;
  unsigned int* smax_enc = (unsigned int*)p; p += 64;
  int* counts  = (int*)p; p += (size_t)Nn * 4;
  int* offsets = (int*)p; p += ((size_t)(Nn + 1) * 4 + 15) & ~(size_t)15;
  int* cursor  = (int*)p; p += (size_t)Nn * 4;
  int* csr     = (int*)p; p += (size_t)EPS * 4;
  int* csr_dst = (int*)p; p += (size_t)EPS * 4;

  // --- CSR build (once; dst is layer-invariant) ---
  hipMemsetAsync(counts, 0, (size_t)Nn * sizeof(int), stream);
  hist_kernel<<<(E + 255) / 256, 256, 0, stream>>>(ei, counts, E);
  scan_kernel<<<1, 1024, 0, stream>>>(counts, offsets, cursor, Nn);
  scatter_kernel<<<(E + 255) / 256, 256, 0, stream>>>(ei, cursor, csr, csr_dst, E);
  pad_kernel<<<(Nn + 255) / 256, 256, 0, stream>>>(counts, offsets, csr, csr_dst, Nn);

  // --- Input conversion ---
  int t4 = Nn * 128 / 4;
  convert_x<<<(t4 + 255) / 256, 256, 0, stream>>>(x, x1b, t4);

  // --- Layers ---
  dim3 ggrid(2, (Nn + 127) / 128);
  int nblk4 = (Nn + 3) / 4;
  for (int l = 0; l < 3; l++) {
    int K = (l == 0) ? 128 : 256;
    const unsigned short* xin = (l == 0) ? x1b : xb;
    transpose_w<<<dim3(K / 64, 8), 256, 0, stream>>>(W[l], SW[l], Bt, K);
    gemm_mfma<<<ggrid, 256, 0, stream>>>(xin, Bt, Sb[l], asrc[l], adst[l],
                                         hb, skipb, sbuf, dbuf, Nn, K);
    hipMemsetAsync(smax_enc, 0, 4 * sizeof(unsigned int), stream);
    smax_kernel<<<(Nn * HEADS + 255) / 256, 256, 0, stream>>>(sbuf, smax_enc, Nn * HEADS);
    edge_e_kernel<<<(EPS + 255) / 256, 256, 0, stream>>>(csr, csr_dst, sbuf, dbuf,
                                                         smax_enc, eexp, EPS, offsets + Nn);
    agg_kernel<<<nblk4, 256, 0, stream>>>(hb, sbuf, dbuf, smax_enc, offsets, csr,
                                          eexp, EPS, bb[l], skipb, (float*)d_out, xb,
                                          Nn, (l == 2) ? 1 : 0);
  }
}

// Round 5
// 672.435 us; speedup vs baseline: 1.1166x; 1.1166x over previous
//
#include <hip/hip_runtime.h>
#include <math.h>

// N=50000, E=800000, IN=128, H=4, C=64, HC=256
#define HEADS 4
#define CH 64
#define HC 256

typedef short bf16x8 __attribute__((ext_vector_type(8)));
typedef float f32x4 __attribute__((ext_vector_type(4)));

__device__ __forceinline__ float leaky02(float x) { return x > 0.f ? x : 0.2f * x; }
__device__ __forceinline__ float bf2f(unsigned short u) {
  unsigned int v = ((unsigned int)u) << 16;
  return __builtin_bit_cast(float, v);
}
__device__ __forceinline__ unsigned short f2bf(float f) {
  unsigned int u = __builtin_bit_cast(unsigned int, f);
  unsigned int r = u + 0x7fffu + ((u >> 16) & 1u);
  return (unsigned short)(r >> 16);
}
__device__ __forceinline__ float decode_max(unsigned int key) {
  unsigned int mb = (key & 0x80000000u) ? (key & 0x7fffffffu) : ~key;
  return __builtin_bit_cast(float, mb);
}
__device__ __forceinline__ float4 bf4_to_f4(ushort4 u) {
  float4 r;
  r.x = bf2f(u.x); r.y = bf2f(u.y); r.z = bf2f(u.z); r.w = bf2f(u.w);
  return r;
}

// ---------------------------------------------------------------------------
// Convert input x fp32 [N*128] -> bf16
// ---------------------------------------------------------------------------
__global__ __launch_bounds__(256) void convert_x(const float* __restrict__ x,
                                                 unsigned short* __restrict__ xb,
                                                 int total4) {
  int i = blockIdx.x * 256 + threadIdx.x;
  if (i >= total4) return;
  float4 v = reinterpret_cast<const float4*>(x)[i];
  ushort4 o;
  o.x = f2bf(v.x); o.y = f2bf(v.y); o.z = f2bf(v.z); o.w = f2bf(v.w);
  reinterpret_cast<ushort4*>(xb)[i] = o;
}

// ---------------------------------------------------------------------------
// LDS-tiled transpose: Bt[512][K] bf16 = [W | SW]^T  (W/SW are [K][256] fp32)
// ---------------------------------------------------------------------------
__global__ __launch_bounds__(256) void transpose_w(const float* __restrict__ W,
                                                   const float* __restrict__ SW,
                                                   unsigned short* __restrict__ Bt, int K) {
  __shared__ unsigned short tile[64][72];
  int k0 = blockIdx.x * 64;
  int c0 = blockIdx.y * 64;
  const float* __restrict__ src = (c0 < 256) ? W : SW;
  int cc = (c0 < 256) ? c0 : c0 - 256;

  int t = threadIdx.x;
  int r = t >> 2, q4 = (t & 3) * 16;
#pragma unroll
  for (int q = 0; q < 4; q++) {
    float4 v = *reinterpret_cast<const float4*>(src + (size_t)(k0 + r) * 256 + cc + q4 + q * 4);
    tile[q4 + q * 4 + 0][r] = f2bf(v.x);
    tile[q4 + q * 4 + 1][r] = f2bf(v.y);
    tile[q4 + q * 4 + 2][r] = f2bf(v.z);
    tile[q4 + q * 4 + 3][r] = f2bf(v.w);
  }
  __syncthreads();
  int c = t >> 2, kq = (t & 3) * 16;
#pragma unroll
  for (int q = 0; q < 2; q++) {
    bf16x8 v = *reinterpret_cast<const bf16x8*>(&tile[c][kq + q * 8]);
    *reinterpret_cast<bf16x8*>(Bt + (size_t)(c0 + c) * K + k0 + kq + q * 8) = v;
  }
}

// ---------------------------------------------------------------------------
// bf16 MFMA GEMM (R3 shape): out[M][512] = x[M][K] @ [W|SW][K][512]
// Block 128x128, 4 waves, wave tile 64x64 (64-reg acc -> 4 waves/SIMD).
//   blockIdx.x 0..1 -> h (bf16); 2..3 -> skip (bf16, +Sb)
// ---------------------------------------------------------------------------
__global__ __launch_bounds__(256) void gemm_mfma(
    const unsigned short* __restrict__ xb, const unsigned short* __restrict__ Bt,
    const float* __restrict__ Sb, unsigned short* __restrict__ h,
    unsigned short* __restrict__ skipb, int M, int K) {
  __shared__ unsigned short As[128 * 40];
  __shared__ unsigned short Bs[128 * 40];

  const int t = threadIdx.x;
  const int rowBase = blockIdx.y * 128;
  const int colBase = blockIdx.x * 128;  // 0..511
  const int w = t >> 6, lane = t & 63;
  const int wr = (w >> 1) * 64, wc = (w & 1) * 64;
  const int lrow = lane & 15, lq = lane >> 4;

  f32x4 acc[4][4];
#pragma unroll
  for (int i = 0; i < 4; i++)
#pragma unroll
    for (int j = 0; j < 4; j++) acc[i][j] = (f32x4){0.f, 0.f, 0.f, 0.f};

  for (int k0 = 0; k0 < K; k0 += 32) {
#pragma unroll
    for (int p = 0; p < 2; p++) {
      int flat = t + p * 256;
      int r = flat >> 2, seg = flat & 3;
      int gr = rowBase + r;
      if (gr >= M) gr = M - 1;
      bf16x8 av = *reinterpret_cast<const bf16x8*>(xb + (size_t)gr * K + k0 + seg * 8);
      *reinterpret_cast<bf16x8*>(&As[r * 40 + seg * 8]) = av;
      int gc = colBase + r;
      bf16x8 bv = *reinterpret_cast<const bf16x8*>(Bt + (size_t)gc * K + k0 + seg * 8);
      *reinterpret_cast<bf16x8*>(&Bs[r * 40 + seg * 8]) = bv;
    }
    __syncthreads();

    bf16x8 af[4], bfr[4];
#pragma unroll
    for (int i = 0; i < 4; i++) {
      af[i]  = *reinterpret_cast<const bf16x8*>(&As[(wr + i * 16 + lrow) * 40 + lq * 8]);
      bfr[i] = *reinterpret_cast<const bf16x8*>(&Bs[(wc + i * 16 + lrow) * 40 + lq * 8]);
    }
#pragma unroll
    for (int i = 0; i < 4; i++)
#pragma unroll
      for (int j = 0; j < 4; j++)
        acc[i][j] = __builtin_amdgcn_mfma_f32_16x16x32_bf16(af[i], bfr[j], acc[i][j], 0, 0, 0);
    __syncthreads();
  }

  // Epilogue: C/D layout col=lane&15, row=(lane>>4)*4+reg
  if (colBase < 256) {
#pragma unroll
    for (int i = 0; i < 4; i++) {
#pragma unroll
      for (int j = 0; j < 4; j++) {
        int gcol = colBase + wc + j * 16 + lrow;
#pragma unroll
        for (int r = 0; r < 4; r++) {
          int grow = rowBase + wr + i * 16 + lq * 4 + r;
          if (grow < M) h[(size_t)grow * 256 + gcol] = f2bf(acc[i][j][r]);
        }
      }
    }
  } else {
#pragma unroll
    for (int i = 0; i < 4; i++) {
#pragma unroll
      for (int j = 0; j < 4; j++) {
        int c = colBase - 256 + wc + j * 16 + lrow;
        float sbv = Sb[c];
#pragma unroll
        for (int r = 0; r < 4; r++) {
          int grow = rowBase + wr + i * 16 + lq * 4 + r;
          if (grow < M) skipb[(size_t)grow * 256 + c] = f2bf(acc[i][j][r] + sbv);
        }
      }
    }
  }
}

// ---------------------------------------------------------------------------
// Attention logits: wave per node, lane covers 4 cols (ushort4).
// ---------------------------------------------------------------------------
__global__ __launch_bounds__(256) void sd_kernel(
    const unsigned short* __restrict__ hb, const float* __restrict__ a_src,
    const float* __restrict__ a_dst, float* __restrict__ s, float* __restrict__ d,
    int Nn) {
  int n = blockIdx.x * 4 + (threadIdx.x >> 6);
  if (n >= Nn) return;
  int lane = threadIdx.x & 63;
  int col = lane * 4;
  float4 h4 = bf4_to_f4(*reinterpret_cast<const ushort4*>(hb + (size_t)n * HC + col));
  float4 as4 = *reinterpret_cast<const float4*>(a_src + col);
  float4 ad4 = *reinterpret_cast<const float4*>(a_dst + col);
  float ps = h4.x * as4.x + h4.y * as4.y + h4.z * as4.z + h4.w * as4.w;
  float pd = h4.x * ad4.x + h4.y * ad4.y + h4.z * ad4.z + h4.w * ad4.w;
#pragma unroll
  for (int off = 1; off < 16; off <<= 1) {
    ps += __shfl_xor(ps, off, 64);
    pd += __shfl_xor(pd, off, 64);
  }
  if ((lane & 15) == 0) {
    int head = lane >> 4;
    s[n * HEADS + head] = ps;
    d[n * HEADS + head] = pd;
  }
}

// ---------------------------------------------------------------------------
// Global per-head max of s (encoded uint for atomicMax; zeroed once with counts)
// ---------------------------------------------------------------------------
__global__ __launch_bounds__(256) void smax_kernel(const float* __restrict__ s,
                                                   unsigned int* __restrict__ smax_enc,
                                                   int total) {
  __shared__ float sm[256];
  int t = threadIdx.x;
  int i = blockIdx.x * 256 + t;
  sm[t] = (i < total) ? s[i] : -1e30f;
  __syncthreads();
  for (int off = 128; off >= 4; off >>= 1) {
    if (t < off) sm[t] = fmaxf(sm[t], sm[t + off]);
    __syncthreads();
  }
  if (t < 4) {
    unsigned int b = __builtin_bit_cast(unsigned int, sm[t]);
    unsigned int key = (b & 0x80000000u) ? ~b : (b | 0x80000000u);
    atomicMax(&smax_enc[t], key);
  }
}

// ---------------------------------------------------------------------------
// CSR build (padded to multiple-of-8 segments)
// ---------------------------------------------------------------------------
__global__ void hist_kernel(const int* __restrict__ ei, int* __restrict__ counts, int E) {
  int e = blockIdx.x * 256 + threadIdx.x;
  if (e < E) atomicAdd(&counts[ei[E + e]], 1);
}

__global__ __launch_bounds__(1024) void scan_kernel(
    const int* __restrict__ counts, int* __restrict__ offsets,
    int* __restrict__ cursor, int n) {
  __shared__ int wsums[16];
  __shared__ int srun;
  int tid = threadIdx.x;
  int lane = tid & 63, wv = tid >> 6;
  if (tid == 0) srun = 0;
  __syncthreads();
  for (int base = 0; base < n; base += 1024) {
    int i = base + tid;
    int c = (i < n) ? counts[i] : 0;
    int v = (c + 7) & ~7;  // pad each segment to multiple of 8
    int incl = v;
#pragma unroll
    for (int off = 1; off < 64; off <<= 1) {
      int tv = __shfl_up(incl, off, 64);
      if (lane >= off) incl += tv;
    }
    if (lane == 63) wsums[wv] = incl;
    __syncthreads();
    if (wv == 0) {
      int wval = (lane < 16) ? wsums[lane] : 0;
      int winc = wval;
#pragma unroll
      for (int off = 1; off < 16; off <<= 1) {
        int tv = __shfl_up(winc, off, 64);
        if (lane >= off) winc += tv;
      }
      if (lane < 16) wsums[lane] = winc - wval;
    }
    __syncthreads();
    int excl = srun + wsums[wv] + incl - v;
    if (i < n) { offsets[i] = excl; cursor[i] = excl; }
    __syncthreads();
    if (tid == 1023) srun = excl + v;
    __syncthreads();
  }
  if (tid == 0) offsets[n] = srun;
}

__global__ void scatter_kernel(const int* __restrict__ ei, int* __restrict__ cursor,
                               int* __restrict__ csr, int* __restrict__ csr_dst, int E) {
  int e = blockIdx.x * 256 + threadIdx.x;
  if (e < E) {
    int dn = ei[E + e];
    int pos = atomicAdd(&cursor[dn], 1);
    csr[pos] = ei[e];
    csr_dst[pos] = dn;
  }
}

__global__ void pad_kernel(const int* __restrict__ counts, const int* __restrict__ offsets,
                           int* __restrict__ csr, int* __restrict__ csr_dst, int Nn) {
  int n = blockIdx.x * 256 + threadIdx.x;
  if (n >= Nn) return;
  int e0 = offsets[n] + counts[n];
  int e1 = offsets[n + 1];
  for (int i = e0; i < e1; i++) { csr[i] = 0; csr_dst[i] = -1; }
}

// ---------------------------------------------------------------------------
// Per-slot softmax numerators, 4 head planes
// ---------------------------------------------------------------------------
__global__ __launch_bounds__(256) void edge_e_kernel(
    const int* __restrict__ csr, const int* __restrict__ csr_dst,
    const float* __restrict__ s, const float* __restrict__ d,
    const unsigned int* __restrict__ smax_enc, float* __restrict__ eexp,
    int eps, const int* __restrict__ etot_ptr) {
  int i = blockIdx.x * 256 + threadIdx.x;
  if (i >= etot_ptr[0]) return;
  int dn = csr_dst[i];
  if (dn < 0) {
    eexp[i] = 0.f; eexp[eps + i] = 0.f; eexp[2 * eps + i] = 0.f; eexp[3 * eps + i] = 0.f;
    return;
  }
  int sn = csr[i];
  float4 s4 = *reinterpret_cast<const float4*>(s + sn * 4);
  float4 d4 = *reinterpret_cast<const float4*>(d + dn * 4);
  eexp[0 * eps + i] = __expf(leaky02(s4.x + d4.x) - leaky02(decode_max(smax_enc[0]) + d4.x));
  eexp[1 * eps + i] = __expf(leaky02(s4.y + d4.y) - leaky02(decode_max(smax_enc[1]) + d4.y));
  eexp[2 * eps + i] = __expf(leaky02(s4.z + d4.z) - leaky02(decode_max(smax_enc[2]) + d4.z));
  eexp[3 * eps + i] = __expf(leaky02(s4.w + d4.w) - leaky02(decode_max(smax_enc[3]) + d4.w));
}

// ---------------------------------------------------------------------------
// Aggregation v4: one wave per node; 32 lanes per edge-row (8 cols/lane, b128
// gathers); halves take interleaved 4-edge groups; combine via shfl_xor(32).
// ---------------------------------------------------------------------------
__global__ __launch_bounds__(256) void agg_kernel(
    const unsigned short* __restrict__ hb, const float* __restrict__ s,
    const float* __restrict__ d, const unsigned int* __restrict__ smax_enc,
    const int* __restrict__ offsets, const int* __restrict__ csr,
    const float* __restrict__ eexp, int eps,
    const float* __restrict__ b, const unsigned short* __restrict__ skipb,
    float* __restrict__ xout_f, unsigned short* __restrict__ xout_b,
    int Nn, int write_f) {
  int n = blockIdx.x * 4 + (threadIdx.x >> 6);
  if (n >= Nn) return;
  int lane = threadIdx.x & 63;
  int sub = lane >> 5;
  int li = lane & 31;
  int head = li >> 3;
  int col = li * 8;

  int beg = offsets[n], end = offsets[n + 1];
  const float* __restrict__ eh = eexp + head * eps;

  float a[8] = {0.f, 0.f, 0.f, 0.f, 0.f, 0.f, 0.f, 0.f};
  float dsum = 0.f;

  for (int i = beg + sub * 4; i < end; i += 8) {
    int4 sn = *reinterpret_cast<const int4*>(csr + i);
    float4 ev = *reinterpret_cast<const float4*>(eh + i);
    bf16x8 u0 = *reinterpret_cast<const bf16x8*>(hb + (size_t)sn.x * HC + col);
    bf16x8 u1 = *reinterpret_cast<const bf16x8*>(hb + (size_t)sn.y * HC + col);
    bf16x8 u2 = *reinterpret_cast<const bf16x8*>(hb + (size_t)sn.z * HC + col);
    bf16x8 u3 = *reinterpret_cast<const bf16x8*>(hb + (size_t)sn.w * HC + col);
#pragma unroll
    for (int k = 0; k < 8; k++) {
      a[k] += ev.x * bf2f((unsigned short)u0[k]) + ev.y * bf2f((unsigned short)u1[k]) +
              ev.z * bf2f((unsigned short)u2[k]) + ev.w * bf2f((unsigned short)u3[k]);
    }
    dsum += ev.x + ev.y + ev.z + ev.w;
  }

#pragma unroll
  for (int k = 0; k < 8; k++) a[k] += __shfl_xor(a[k], 32, 64);
  dsum += __shfl_xor(dsum, 32, 64);

  // self loop
  float sv = s[n * 4 + head], dv = d[n * 4 + head];
  float m = leaky02(decode_max(smax_enc[head]) + dv);
  float es = __expf(leaky02(sv + dv) - m);
  bf16x8 hs = *reinterpret_cast<const bf16x8*>(hb + (size_t)n * HC + col);
#pragma unroll
  for (int k = 0; k < 8; k++) a[k] += es * bf2f((unsigned short)hs[k]);
  dsum += es;

  if (sub == 0) {
    float inv = 1.f / (dsum + 1e-16f);
    bf16x8 sk = *reinterpret_cast<const bf16x8*>(skipb + (size_t)n * HC + col);
    float4 b0 = *reinterpret_cast<const float4*>(b + col);
    float4 b1 = *reinterpret_cast<const float4*>(b + col + 4);
    float bv[8] = {b0.x, b0.y, b0.z, b0.w, b1.x, b1.y, b1.z, b1.w};
    float res[8];
#pragma unroll
    for (int k = 0; k < 8; k++) {
      float v = a[k] * inv + bv[k] + bf2f((unsigned short)sk[k]);
      res[k] = v > 0.f ? v : expm1f(v);
    }
    if (write_f) {
      float4 r0 = make_float4(res[0], res[1], res[2], res[3]);
      float4 r1 = make_float4(res[4], res[5], res[6], res[7]);
      *reinterpret_cast<float4*>(xout_f + (size_t)n * HC + col) = r0;
      *reinterpret_cast<float4*>(xout_f + (size_t)n * HC + col + 4) = r1;
    } else {
      bf16x8 o;
#pragma unroll
      for (int k = 0; k < 8; k++) o[k] = (short)f2bf(res[k]);
      *reinterpret_cast<bf16x8*>(xout_b + (size_t)n * HC + col) = o;
    }
  }
}

// ---------------------------------------------------------------------------
extern "C" void kernel_launch(void* const* d_in, const int* in_sizes, int n_in,
                              void* d_out, int out_size, void* d_ws, size_t ws_size,
                              hipStream_t stream) {
  const float* x = (const float*)d_in[0];
  const int* ei = (const int*)d_in[1];
  const int Nn = in_sizes[0] / 128;  // 50000
  const int E = in_sizes[1] / 2;     // 800000
  const int EPS = E + 7 * Nn;        // max padded CSR size (pad-8)

  const float* W[3]; const float* asrc[3]; const float* adst[3];
  const float* bb[3]; const float* SW[3]; const float* Sb[3];
  for (int l = 0; l < 3; l++) {
    W[l]    = (const float*)d_in[2 + 6 * l + 0];
    asrc[l] = (const float*)d_in[2 + 6 * l + 1];
    adst[l] = (const float*)d_in[2 + 6 * l + 2];
    bb[l]   = (const float*)d_in[2 + 6 * l + 3];
    SW[l]   = (const float*)d_in[2 + 6 * l + 4];
    Sb[l]   = (const float*)d_in[2 + 6 * l + 5];
  }

  // Workspace layout (16B aligned chunks). counts and smax_enc adjacent so a
  // single memset clears both (smax uses 4 slots per layer, 12 total).
  char* p = (char*)d_ws;
  unsigned short* hb    = (unsigned short*)p; p += (size_t)Nn * HC * 2;
  unsigned short* xb    = (unsigned short*)p; p += (size_t)Nn * HC * 2;
  unsigned short* x1b   = (unsigned short*)p; p += (size_t)Nn * 128 * 2;
  unsigned short* Bt    = (unsigned short*)p; p += (size_t)512 * 256 * 2;
  unsigned short* skipb = (unsigned short*)p; p += (size_t)Nn * HC * 2;
  float* sbuf  = (float*)p; p += (size_t)Nn * HEADS * 4;
  float* dbuf  = (float*)p; p += (size_t)Nn * HEADS * 4;
  float* eexp  = (float*)p; p += (size_t)4 * EPS * 4;
  int* counts  = (int*)p; p += (size_t)Nn * 4;
  unsigned int* smax_enc = (unsigned int*)p; p += 64;
  int* offsets = (int*)p; p += ((size_t)(Nn + 1) * 4 + 15) & ~(size_t)15;
  int* cursor  = (int*)p; p += (size_t)Nn * 4;
  int* csr     = (int*)p; p += (size_t)EPS * 4;
  int* csr_dst = (int*)p; p += (size_t)EPS * 4;

  // --- CSR build (once; dst is layer-invariant). One memset covers counts+smax.
  hipMemsetAsync(counts, 0, (size_t)Nn * 4 + 64, stream);
  hist_kernel<<<(E + 255) / 256, 256, 0, stream>>>(ei, counts, E);
  scan_kernel<<<1, 1024, 0, stream>>>(counts, offsets, cursor, Nn);
  scatter_kernel<<<(E + 255) / 256, 256, 0, stream>>>(ei, cursor, csr, csr_dst, E);
  pad_kernel<<<(Nn + 255) / 256, 256, 0, stream>>>(counts, offsets, csr, csr_dst, Nn);

  // --- Input conversion ---
  int t4 = Nn * 128 / 4;
  convert_x<<<(t4 + 255) / 256, 256, 0, stream>>>(x, x1b, t4);

  // --- Layers ---
  dim3 ggrid(4, (Nn + 127) / 128);
  int nblk4 = (Nn + 3) / 4;
  for (int l = 0; l < 3; l++) {
    int K = (l == 0) ? 128 : 256;
    const unsigned short* xin = (l == 0) ? x1b : xb;
    unsigned int* sme = smax_enc + 4 * l;
    transpose_w<<<dim3(K / 64, 8), 256, 0, stream>>>(W[l], SW[l], Bt, K);
    gemm_mfma<<<ggrid, 256, 0, stream>>>(xin, Bt, Sb[l], hb, skipb, Nn, K);
    sd_kernel<<<nblk4, 256, 0, stream>>>(hb, asrc[l], adst[l], sbuf, dbuf, Nn);
    smax_kernel<<<(Nn * HEADS + 255) / 256, 256, 0, stream>>>(sbuf, sme, Nn * HEADS);
    edge_e_kernel<<<(EPS + 255) / 256, 256, 0, stream>>>(csr, csr_dst, sbuf, dbuf,
                                                         sme, eexp, EPS, offsets + Nn);
    agg_kernel<<<nblk4, 256, 0, stream>>>(hb, sbuf, dbuf, sme, offsets, csr,
                                          eexp, EPS, bb[l], skipb, (float*)d_out, xb,
                                          Nn, (l == 2) ? 1 : 0);
  }
}